// Round 1
// baseline (104.621 us; speedup 1.0000x reference)
//
#include <hip/hip_runtime.h>
#include <stdint.h>

#define N_EXPERTS 20
#define DIM 32
#define NB1 256   // blocks in count/scatter kernels
#define T1 256    // threads per block

using frag_ab = __attribute__((ext_vector_type(8))) short;  // 8 bf16
using frag_cd = __attribute__((ext_vector_type(4))) float;  // 4 fp32

static __device__ __forceinline__ short f2bf(float f) {
    union { float f; uint32_t u; } v; v.f = f;
    uint32_t u = v.u;
    uint32_t r = (u + 0x7FFFu + ((u >> 16) & 1u)) >> 16;   // RNE
    return (short)(uint16_t)r;
}

// ---------------- K1: histogram + combined-weight precompute ----------------
// M[e] = W0[e] @ W1[e]  (bf16), c[e] = W0[e] @ b1[e] + b0[e]  (fp32)
__global__ __launch_bounds__(T1) void k_prep(
    const float* __restrict__ W1, const float* __restrict__ b1,
    const float* __restrict__ W0, const float* __restrict__ b0,
    const int* __restrict__ pos, int B,
    int* __restrict__ cnt, unsigned short* __restrict__ Mbf,
    float* __restrict__ cvec)
{
    __shared__ int hist[N_EXPERTS];
    int b = blockIdx.x, t = threadIdx.x;
    if (t < N_EXPERTS) hist[t] = 0;
    __syncthreads();

    int per  = (B + NB1 - 1) / NB1;
    int base = b * per;
    int end  = min(base + per, B);
    for (int i = base + t; i < end; i += T1)
        atomicAdd(&hist[pos[i]], 1);

    if (b < N_EXPERTS) {
        const float* w1 = W1 + b * 1024;
        const float* w0 = W0 + b * 1024;
        for (int idx = t; idx < 1024; idx += T1) {
            int o = idx >> 5, i = idx & 31;
            float s = 0.f;
            #pragma unroll
            for (int k = 0; k < 32; k++) s += w0[o*32 + k] * w1[k*32 + i];
            Mbf[b*1024 + o*32 + i] = (unsigned short)f2bf(s);
        }
        if (t < DIM) {
            float s = b0[b*32 + t];
            #pragma unroll
            for (int k = 0; k < 32; k++) s += w0[t*32 + k] * b1[b*32 + k];
            cvec[b*32 + t] = s;
        }
    }
    __syncthreads();
    if (t < N_EXPERTS) cnt[b*N_EXPERTS + t] = hist[t];
}

// ---------------- K2: per-block offsets + scatter sample indices ----------------
__global__ __launch_bounds__(T1) void k_scatter(
    const int* __restrict__ pos, int B,
    const int* __restrict__ cnt,
    int* __restrict__ idxArr, int* __restrict__ binStart)
{
    __shared__ int lbin[N_EXPERTS];
    __shared__ int tot[N_EXPERTS];
    int b = blockIdx.x, t = threadIdx.x;

    if (t < N_EXPERTS) {
        int pre = 0, total = 0;
        for (int bb = 0; bb < NB1; bb++) {
            int v = cnt[bb*N_EXPERTS + t];
            if (bb < b) pre += v;
            total += v;
        }
        lbin[t] = pre; tot[t] = total;
    }
    __syncthreads();
    if (t == 0) {
        int acc = 0;
        for (int e = 0; e < N_EXPERTS; e++) {
            int te = tot[e];
            lbin[e] += acc;                    // binStart[e] + pre_b[e]
            if (b == 0) binStart[e] = acc;
            acc += te;
        }
        if (b == 0) binStart[N_EXPERTS] = acc; // == B
    }
    __syncthreads();

    int per  = (B + NB1 - 1) / NB1;
    int base = b * per;
    int end  = min(base + per, B);
    for (int i = base + t; i < end; i += T1) {
        int e = pos[i];
        int slot = atomicAdd(&lbin[e], 1);
        idxArr[slot] = i;
    }
}

// ---------------- K3: expert-uniform MFMA GEMM + bias + L2-normalize ----------------
// out[s] = normalize(M[e] @ x[s] + c[e]) for samples in sorted-bucket order.
__global__ __launch_bounds__(T1) void k_gemm(
    const float* __restrict__ x, const int* __restrict__ idxArr,
    const int* __restrict__ binStart,
    const unsigned short* __restrict__ Mbf, const float* __restrict__ cvec,
    float* __restrict__ out, int B)
{
    int t = threadIdx.x;
    int lane = t & 63, wave = t >> 6;

    int bs[N_EXPERTS + 1];
    #pragma unroll
    for (int e = 0; e <= N_EXPERTS; e++) bs[e] = binStart[e];

    int expert = -1, chunk = 0, acc = 0;
    #pragma unroll
    for (int e = 0; e < N_EXPERTS; e++) {
        int nb = (bs[e+1] - bs[e] + 255) >> 8;   // 256 samples per block
        if (expert < 0 && (int)blockIdx.x < acc + nb) { expert = e; chunk = (int)blockIdx.x - acc; }
        acc += nb;
    }
    if (expert < 0) return;
    int e = expert;
    int begin = bs[e] + chunk * 256;
    int bend  = bs[e+1];

    int n = lane & 15, q = lane >> 4;

    // Block-uniform B-fragments: B[k][n] = M[n][k]; lane holds k = q*8+j, col n (and n+16).
    frag_ab bf0 = *(const frag_ab*)(Mbf + e*1024 + n*32 + q*8);
    frag_ab bf1 = *(const frag_ab*)(Mbf + e*1024 + (n+16)*32 + q*8);
    float c0 = cvec[e*32 + n];
    float c1 = cvec[e*32 + 16 + n];

    int s0 = begin + wave * 64;
    #pragma unroll
    for (int tt = 0; tt < 4; tt++) {
        int tb = s0 + tt * 16;
        if (tb >= bend) break;              // wave-uniform condition

        // A-fragment: A[m=lane&15][k=q*8+j] = x[sample tb+m][k]
        int srow = tb + n;
        int sidx = idxArr[min(srow, bend - 1)];
        const float* xr = x + (size_t)sidx * 32 + q * 8;
        float4 xa = *(const float4*)xr;
        float4 xb = *(const float4*)(xr + 4);
        frag_ab af;
        af[0]=f2bf(xa.x); af[1]=f2bf(xa.y); af[2]=f2bf(xa.z); af[3]=f2bf(xa.w);
        af[4]=f2bf(xb.x); af[5]=f2bf(xb.y); af[6]=f2bf(xb.z); af[7]=f2bf(xb.w);

        frag_cd z = {0.f, 0.f, 0.f, 0.f};
        frag_cd d0 = __builtin_amdgcn_mfma_f32_16x16x32_bf16(af, bf0, z, 0, 0, 0);
        frag_cd d1 = __builtin_amdgcn_mfma_f32_16x16x32_bf16(af, bf1, z, 0, 0, 0);

        // C/D: col = lane&15 (=n), row = q*4 + r (= sample within tile)
        #pragma unroll
        for (int r = 0; r < 4; r++) {
            int orow = tb + q * 4 + r;
            float v0 = d0[r] + c0;
            float v1 = d1[r] + c1;
            float ss = v0*v0 + v1*v1;
            ss += __shfl_xor(ss, 1);
            ss += __shfl_xor(ss, 2);
            ss += __shfl_xor(ss, 4);
            ss += __shfl_xor(ss, 8);        // full 32-dim sum-of-squares per sample
            float scale = 1.0f / fmaxf(sqrtf(ss), 1e-12f);
            if (orow < bend) {
                int oi = idxArr[orow];
                out[(size_t)oi * 32 + n]      = v0 * scale;
                out[(size_t)oi * 32 + 16 + n] = v1 * scale;
            }
        }
    }
}

extern "C" void kernel_launch(void* const* d_in, const int* in_sizes, int n_in,
                              void* d_out, int out_size, void* d_ws, size_t ws_size,
                              hipStream_t stream) {
    const float* x  = (const float*)d_in[0];
    const float* W1 = (const float*)d_in[1];
    const float* b1 = (const float*)d_in[2];
    const float* W0 = (const float*)d_in[3];
    const float* b0 = (const float*)d_in[4];
    const int*  pos = (const int*)d_in[5];
    float* out = (float*)d_out;
    int B = in_sizes[0] / DIM;   // 131072

    // ws layout
    char* ws = (char*)d_ws;
    int* idxArr   = (int*)ws;                                          // B ints
    size_t off    = (size_t)B * 4;
    int* cnt      = (int*)(ws + off);       off += (size_t)NB1 * N_EXPERTS * 4;
    int* binStart = (int*)(ws + off);       off += 128;                // 21 ints, padded
    unsigned short* Mbf = (unsigned short*)(ws + off); off += (size_t)N_EXPERTS * 1024 * 2;
    float* cvec   = (float*)(ws + off);

    k_prep<<<NB1, T1, 0, stream>>>(W1, b1, W0, b0, pos, B, cnt, Mbf, cvec);
    k_scatter<<<NB1, T1, 0, stream>>>(pos, B, cnt, idxArr, binStart);
    int nblk = (B + 255) / 256 + N_EXPERTS;   // padded for per-bucket ceil
    k_gemm<<<nblk, T1, 0, stream>>>(x, idxArr, binStart, Mbf, cvec, out, B);
}

// Round 2
// 89.748 us; speedup vs baseline: 1.1657x; 1.1657x over previous
//
#include <hip/hip_runtime.h>
#include <stdint.h>

#define N_EXPERTS 20
#define DIM 32
#define SPB 256            // samples per block (== block threads)
#define MAIN_T 256
#define MROW 40            // LDS M row stride in shorts (80 B: 16B-aligned rows, near-conflict-free b128)
#define MAX_TILES 48

using frag_ab = __attribute__((ext_vector_type(8))) short;  // 8 bf16
using frag_cd = __attribute__((ext_vector_type(4))) float;  // 4 fp32

static __device__ __forceinline__ short f2bf(float f) {
    union { float f; uint32_t u; } v; v.f = f;
    uint32_t u = v.u;
    return (short)(uint16_t)((u + 0x7FFFu + ((u >> 16) & 1u)) >> 16);  // RNE
}

// ---------------- K1: combined-weight precompute ----------------
// M[e] = W0[e] @ W1[e]  (bf16), c[e] = W0[e] @ b1[e] + b0[e]  (fp32)
__global__ __launch_bounds__(256) void k_prep(
    const float* __restrict__ W1, const float* __restrict__ b1,
    const float* __restrict__ W0, const float* __restrict__ b0,
    unsigned short* __restrict__ Mbf, float* __restrict__ cvec)
{
    __shared__ float s1[1024], s0[1024];
    int e = blockIdx.x, t = threadIdx.x;
    const float* w1 = W1 + e * 1024;
    const float* w0 = W0 + e * 1024;
    for (int i = t; i < 1024; i += 256) { s1[i] = w1[i]; s0[i] = w0[i]; }
    __syncthreads();
    for (int idx = t; idx < 1024; idx += 256) {
        int o = idx >> 5, i = idx & 31;
        float s = 0.f;
        #pragma unroll
        for (int k = 0; k < 32; k++) s += s0[o*32 + k] * s1[k*32 + i];
        Mbf[e*1024 + o*32 + i] = (unsigned short)f2bf(s);
    }
    if (t < DIM) {
        float s = b0[e*32 + t];
        #pragma unroll
        for (int k = 0; k < 32; k++) s += s0[t*32 + k] * b1[e*32 + k];
        cvec[e*32 + t] = s;
    }
}

// ---------------- K2: block-local bucket + MFMA + normalize ----------------
__global__ __launch_bounds__(MAIN_T) void k_moe(
    const float* __restrict__ x, const int* __restrict__ pos,
    const unsigned short* __restrict__ Mbf, const float* __restrict__ cvec,
    float* __restrict__ out, int B)
{
    __shared__ unsigned short Ms[N_EXPERTS * 32 * MROW];   // 51200 B
    __shared__ float cs[N_EXPERTS * 32];
    __shared__ int hist[N_EXPERTS];
    __shared__ int lstart[N_EXPERTS + 1];
    __shared__ int cursor[N_EXPERTS];
    __shared__ int lidx[SPB];
    __shared__ int tileE[MAX_TILES], tileB[MAX_TILES];
    __shared__ int ntiles;

    int t = threadIdx.x;
    int base = blockIdx.x * SPB;
    int S = min(SPB, B - base);
    if (S <= 0) return;

    if (t < N_EXPERTS) hist[t] = 0;
    __syncthreads();

    // stage M (20*1024 shorts = 10240 dwords) into padded LDS rows + cs
    {
        const uint32_t* msrc = (const uint32_t*)Mbf;
        uint32_t* mdst = (uint32_t*)Ms;
        for (int d = t; d < N_EXPERTS * 512; d += MAIN_T) {
            int e = d >> 9, rem = d & 511;
            int n = rem >> 4, c = rem & 15;
            mdst[e * (32 * MROW / 2) + n * (MROW / 2) + c] = msrc[d];
        }
        for (int i = t; i < N_EXPERTS * 32; i += MAIN_T) cs[i] = cvec[i];
    }
    // histogram (1 sample / thread)
    int my_e = -1;
    if (t < S) {
        my_e = pos[base + t];
        atomicAdd(&hist[my_e], 1);
    }
    __syncthreads();

    int lane = t & 63, wave = t >> 6;

    // wave-0 shuffle scan: bucket starts + tile table
    if (wave == 0) {
        int e = lane;
        int h = (e < N_EXPERTS) ? hist[e] : 0;
        int s = h;
        #pragma unroll
        for (int d = 1; d < 32; d <<= 1) { int v = __shfl_up(s, d); if (lane >= d) s += v; }
        int pre = s - h;                       // exclusive prefix of counts
        int ntl = (h + 15) >> 4;
        int ts = ntl;
        #pragma unroll
        for (int d = 1; d < 32; d <<= 1) { int v = __shfl_up(ts, d); if (lane >= d) ts += v; }
        int tpre = ts - ntl;                   // exclusive prefix of tile counts
        if (e < N_EXPERTS) {
            lstart[e] = pre; cursor[e] = pre;
            for (int k = 0; k < ntl; k++) { tileE[tpre + k] = e; tileB[tpre + k] = pre + 16 * k; }
            if (e == N_EXPERTS - 1) { lstart[N_EXPERTS] = pre + h; ntiles = tpre + ntl; }
        }
    }
    __syncthreads();

    // scatter local indices
    if (t < S) {
        int slot = atomicAdd(&cursor[my_e], 1);
        lidx[slot] = t;
    }
    __syncthreads();

    int nt = ntiles;
    int n = lane & 15, q = lane >> 4;

    // software-pipelined tile loop (prefetch next tile's x)
    int ti = wave;
    float4 xa, xb;
    int cur_e = 0, cur_tb = 0, cur_bend = 0;
    if (ti < nt) {
        cur_e = tileE[ti]; cur_tb = tileB[ti]; cur_bend = lstart[cur_e + 1];
        int slot = min(cur_tb + n, cur_bend - 1);
        int l = lidx[slot];
        const float* xr = x + (size_t)(base + l) * 32 + q * 8;
        xa = *(const float4*)xr; xb = *(const float4*)(xr + 4);
    }
    for (; ti < nt; ti += 4) {
        int e = cur_e, tb = cur_tb, bend = cur_bend;
        float4 a0 = xa, a1 = xb;
        int tj = ti + 4;
        if (tj < nt) {
            cur_e = tileE[tj]; cur_tb = tileB[tj]; cur_bend = lstart[cur_e + 1];
            int slot = min(cur_tb + n, cur_bend - 1);
            int l = lidx[slot];
            const float* xr = x + (size_t)(base + l) * 32 + q * 8;
            xa = *(const float4*)xr; xb = *(const float4*)(xr + 4);
        }

        // B-fragments from LDS: B[k=q*8+j][col] = M[col][k]
        const unsigned short* mrow = Ms + e * 32 * MROW;
        frag_ab bf0 = *(const frag_ab*)(mrow + n * MROW + q * 8);
        frag_ab bf1 = *(const frag_ab*)(mrow + (n + 16) * MROW + q * 8);
        float c0 = cs[e * 32 + n];
        float c1 = cs[e * 32 + 16 + n];

        frag_ab af;
        af[0] = f2bf(a0.x); af[1] = f2bf(a0.y); af[2] = f2bf(a0.z); af[3] = f2bf(a0.w);
        af[4] = f2bf(a1.x); af[5] = f2bf(a1.y); af[6] = f2bf(a1.z); af[7] = f2bf(a1.w);

        frag_cd z = {0.f, 0.f, 0.f, 0.f};
        frag_cd d0 = __builtin_amdgcn_mfma_f32_16x16x32_bf16(af, bf0, z, 0, 0, 0);
        frag_cd d1 = __builtin_amdgcn_mfma_f32_16x16x32_bf16(af, bf1, z, 0, 0, 0);

        // C/D: col = lane&15 (=n), row-in-tile = q*4 + r
        #pragma unroll
        for (int r = 0; r < 4; r++) {
            int os = tb + q * 4 + r;
            float v0 = d0[r] + c0;
            float v1 = d1[r] + c1;
            float ss = v0 * v0 + v1 * v1;
            ss += __shfl_xor(ss, 1);
            ss += __shfl_xor(ss, 2);
            ss += __shfl_xor(ss, 4);
            ss += __shfl_xor(ss, 8);          // 32-dim sum of squares per sample
            float sc = rsqrtf(fmaxf(ss, 1e-24f));
            if (os < bend) {
                int lo = lidx[os];
                float* op = out + (size_t)(base + lo) * 32;
                op[n]      = v0 * sc;
                op[16 + n] = v1 * sc;
            }
        }
    }
}

extern "C" void kernel_launch(void* const* d_in, const int* in_sizes, int n_in,
                              void* d_out, int out_size, void* d_ws, size_t ws_size,
                              hipStream_t stream) {
    const float* x  = (const float*)d_in[0];
    const float* W1 = (const float*)d_in[1];
    const float* b1 = (const float*)d_in[2];
    const float* W0 = (const float*)d_in[3];
    const float* b0 = (const float*)d_in[4];
    const int*  pos = (const int*)d_in[5];
    float* out = (float*)d_out;
    int B = in_sizes[0] / DIM;   // 131072

    char* ws = (char*)d_ws;
    unsigned short* Mbf = (unsigned short*)ws;                       // 20*1024 shorts
    float* cvec = (float*)(ws + (size_t)N_EXPERTS * 1024 * 2);       // 20*32 floats

    k_prep<<<N_EXPERTS, 256, 0, stream>>>(W1, b1, W0, b0, Mbf, cvec);
    int nblk = (B + SPB - 1) / SPB;
    k_moe<<<nblk, MAIN_T, 0, stream>>>(x, pos, Mbf, cvec, out, B);
}